// Round 4
// baseline (56990.991 us; speedup 1.0000x reference)
//
#include <hip/hip_runtime.h>
#include <cstdint>
#include <cstddef>

// Decoder (LFADS-like): B=512, T=200.
// Persistent kernel v2: 192 blocks x 256 threads (1/CU, co-resident, no LDS).
// 4 dependent bf16-MFMA GEMM stages per step, separated by two-level
// device-wide barriers built ONLY from relaxed agent-scope atomics (no
// acquire/release cache maintenance -> no L2 invalidate storms).
// Inter-stage activations: relaxed agent atomics (sc1, coherent via IF).
// Weights: plain cached loads, L2-resident across all 800 stages
// (bijective XCD-chunked bn mapping, ~1.9 MB/XCD).
// MFMA operands swapped (mfma(W,A)) so each lane's output quad is 4
// consecutive columns -> bf16 activations pack 2-per-dword atomic stores.
// Precomposed weights:
//   W'  = com_W @ gen_K[:32]    (co_mean folded into generator input GEMM)
//   W'' = fac_Wn @ con_K[128:]  (factor path folded into controller GEMM;
//                                fac_Wn columns appended -> facs output free)

#define B_   512
#define T_   200
#define CI_  128
#define EXT_ 8
#define GEN_ 800
#define CON_ 400
#define CO_  32
#define FAC_ 128
#define NBLK 192

typedef __attribute__((ext_vector_type(8))) short short8;
typedef __attribute__((ext_vector_type(4))) float f32x4;
typedef __attribute__((ext_vector_type(4))) unsigned short us4;

__device__ __forceinline__ unsigned short f2bf(float f) {
  unsigned int u = __float_as_uint(f);
  u += 0x7FFFu + ((u >> 16) & 1u);   // RNE
  return (unsigned short)(u >> 16);
}
__device__ __forceinline__ unsigned pk2(float a, float b) {
  return (unsigned)f2bf(a) | ((unsigned)f2bf(b) << 16);
}
__device__ __forceinline__ float sigm(float x) { return 1.0f / (1.0f + __expf(-x)); }

// relaxed agent-scope coherent access (sc1; no cache-maintenance fences)
__device__ __forceinline__ float aldf(const float* p) {
  return __hip_atomic_load(p, __ATOMIC_RELAXED, __HIP_MEMORY_SCOPE_AGENT);
}
__device__ __forceinline__ void astf(float* p, float v) {
  __hip_atomic_store(p, v, __ATOMIC_RELAXED, __HIP_MEMORY_SCOPE_AGENT);
}
__device__ __forceinline__ void astu(unsigned* p, unsigned v) {
  __hip_atomic_store(p, v, __ATOMIC_RELAXED, __HIP_MEMORY_SCOPE_AGENT);
}
__device__ __forceinline__ short8 cld8(const void* p) {
  const unsigned* u = (const unsigned*)p;
  union { unsigned w[4]; short8 v; } r;
  #pragma unroll
  for (int i = 0; i < 4; ++i)
    r.w[i] = __hip_atomic_load(u + i, __ATOMIC_RELAXED, __HIP_MEMORY_SCOPE_AGENT);
  return r.v;
}

// ---------------- setup kernels ----------------

__global__ void k_facnorm(const float* __restrict__ facW, float* __restrict__ facWn) {
  int j = blockIdx.x;            // 0..127 (column)
  int l = threadIdx.x;           // 64 threads = 1 wave
  float s = 0.f;
  for (int k = l; k < GEN_; k += 64) { float v = facW[(size_t)k*FAC_ + j]; s += v*v; }
  #pragma unroll
  for (int off = 32; off > 0; off >>= 1) s += __shfl_down(s, off, 64);
  float inv = 1.0f / sqrtf(__shfl(s, 0, 64));
  for (int k = l; k < GEN_; k += 64) facWn[(size_t)k*FAC_ + j] = facW[(size_t)k*FAC_ + j] * inv;
}

__global__ void k_w2(const float* __restrict__ facWn, const float* __restrict__ conK,
                     float* __restrict__ tmp2) {
  int n = blockIdx.x*256 + threadIdx.x; if (n >= 1200) return;
  int kp = blockIdx.y;
  const float* fr = facWn + (size_t)kp*FAC_;
  float s = 0.f;
  for (int j = 0; j < FAC_; ++j) s = fmaf(fr[j], conK[(size_t)(CI_+j)*1200 + n], s);
  tmp2[(size_t)kp*1200 + n] = s;
}

__global__ void k_w1(const float* __restrict__ comW, const float* __restrict__ genK,
                     float* __restrict__ tmp1) {
  int n = blockIdx.x*256 + threadIdx.x; if (n >= 2400) return;
  int k = blockIdx.y;
  const float* cr = comW + (size_t)k*CO_;
  float s = 0.f;
  for (int j = 0; j < CO_; ++j) s = fmaf(cr[j], genK[(size_t)j*2400 + n], s);
  tmp1[(size_t)k*2400 + n] = s;
}

__global__ void k_cvt(const float* __restrict__ ci, const float* __restrict__ ext,
                      unsigned short* __restrict__ cib, unsigned short* __restrict__ extb) {
  const long n1 = (long)B_*T_*CI_/4;
  const long n2 = (long)B_*T_*EXT_/4;
  for (long i = blockIdx.x*(long)blockDim.x + threadIdx.x; i < n1+n2;
       i += (long)gridDim.x*blockDim.x) {
    if (i < n1) {
      float4 f = reinterpret_cast<const float4*>(ci)[i];
      us4 u; u.x=f2bf(f.x); u.y=f2bf(f.y); u.z=f2bf(f.z); u.w=f2bf(f.w);
      reinterpret_cast<us4*>(cib)[i] = u;
    } else {
      long k = i - n1;
      float4 f = reinterpret_cast<const float4*>(ext)[k];
      us4 u; u.x=f2bf(f.x); u.y=f2bf(f.y); u.z=f2bf(f.z); u.w=f2bf(f.w);
      reinterpret_cast<us4*>(extb)[k] = u;
    }
  }
}

__global__ void k_init(const float* __restrict__ conh0, const float* __restrict__ geninit,
                       const float* __restrict__ conb, const float* __restrict__ genb,
                       const float* __restrict__ comb, const float* __restrict__ genK,
                       float* __restrict__ bczr, float* __restrict__ bgzr,
                       float* __restrict__ conh, unsigned short* __restrict__ agzr,
                       float* __restrict__ genh, unsigned short* __restrict__ genhb,
                       unsigned short* __restrict__ achh,
                       unsigned short* __restrict__ zbuf, unsigned* __restrict__ gs) {
  const long R0=1344, R1=2432, R2=(long)B_*CON_, R3=(long)B_*CON_,
             R4=(long)B_*GEN_, R5=(long)B_*GEN_, R6=(long)B_*416, R7=64, R8=256;
  const long total = R0+R1+R2+R3+R4+R5+R6+R7+R8;
  for (long idx = blockIdx.x*(long)blockDim.x + threadIdx.x; idx < total;
       idx += (long)gridDim.x*blockDim.x) {
    long i = idx;
    if (i < R0) { bczr[i] = (i < 1200) ? conb[i] : 0.f; continue; }
    i -= R0;
    if (i < R1) {
      float s = 0.f;
      if (i < 2400) { s = genb[i]; for (int j=0;j<32;++j) s = fmaf(comb[j], genK[(size_t)j*2400 + i], s); }
      bgzr[i] = s; continue;
    }
    i -= R1;
    if (i < R2) { conh[i] = conh0[i % CON_]; continue; }
    i -= R2;
    if (i < R3) { agzr[i] = f2bf(conh0[i % CON_]); continue; }
    i -= R3;
    if (i < R4) { genh[i] = geninit[i]; continue; }
    i -= R4;
    if (i < R5) { genhb[i] = f2bf(geninit[i]); continue; }
    i -= R5;
    if (i < R6) { achh[i] = 0; continue; }
    i -= R6;
    if (i < R7) { zbuf[i] = 0; continue; }
    i -= R7;
    gs[i] = 0;
  }
}

// build transposed bf16 weights: dst[n][k] = fetch(k, n)
struct BTArgs {
  int mode, K;
  const float* conK; const float* conR; const float* genK; const float* genR;
  const float* facWn; const float* tmp1; const float* tmp2;
  unsigned short* dst;
};

__device__ __forceinline__ float bt_fetch(const BTArgs& a, int k, int n) {
  switch (a.mode) {
    case 0: // W_czr^T: K=1344 (ci128|gen800|con416), N=1408 (z400|r400|xh400|fac128|pad)
      if (n < 1200) {
        if (k < 128)  return a.conK[(size_t)k*1200 + n];
        if (k < 928)  return a.tmp2[(size_t)(k-128)*1200 + n];
        if (k < 1328) return (n < 800) ? a.conR[(size_t)(k-928)*1200 + n] : 0.f;
        return 0.f;
      }
      if (n < 1328) return (k >= 128 && k < 928) ? a.facWn[(size_t)(k-128)*FAC_ + (n-1200)] : 0.f;
      return 0.f;
    case 1: // W_chh^T: con_R[:,800:1200]
      return (k < 400 && n < 400) ? a.conR[(size_t)k*1200 + 800 + n] : 0.f;
    case 2: // W_gzr^T: K=1216 (conh400|ext8|pad8|genh800), N=2432 (z800|r800|xh800|pad)
      if (n >= 2400) return 0.f;
      if (k < 400)  return a.tmp1[(size_t)k*2400 + n];
      if (k < 408)  return a.genK[(size_t)(32 + k - 400)*2400 + n];
      if (k < 416)  return 0.f;
      if (k < 1216) return (n < 1600) ? a.genR[(size_t)(k-416)*2400 + n] : 0.f;
      return 0.f;
    case 3: // W_ghh^T: gen_R[:,1600:2400]
      return (n < 800 && k < 800) ? a.genR[(size_t)k*2400 + 1600 + n] : 0.f;
    default: // fac_Wn^T [128][800]
      return (k < 800 && n < 128) ? a.facWn[(size_t)k*FAC_ + n] : 0.f;
  }
}

__global__ __launch_bounds__(256) void k_buildT(BTArgs a) {
  __shared__ float tile[64][65];
  int k0 = blockIdx.x*64, n0 = blockIdx.y*64;
  int tid = threadIdx.x;
  int rr = tid >> 2, cc = (tid & 3) * 16;
  #pragma unroll 4
  for (int i = 0; i < 16; ++i) tile[rr][cc+i] = bt_fetch(a, k0+rr, n0+cc+i);
  __syncthreads();
  int n = n0 + rr;
  if (k0 + cc < a.K) {    // K is a multiple of 16
    short8 v0, v1;
    #pragma unroll
    for (int i = 0; i < 8; ++i) v0[i] = (short)f2bf(tile[cc+i][rr]);
    #pragma unroll
    for (int i = 0; i < 8; ++i) v1[i] = (short)f2bf(tile[cc+8+i][rr]);
    *reinterpret_cast<short8*>(&a.dst[(size_t)n*a.K + k0 + cc])     = v0;
    *reinterpret_cast<short8*>(&a.dst[(size_t)n*a.K + k0 + cc + 8]) = v1;
  }
}

// ---------------- persistent decoder ----------------

struct PA {
  const unsigned short* cib; const unsigned short* extb;
  const unsigned short* wczr; const unsigned short* wchh; const unsigned short* wgzr;
  const unsigned short* wghh; const unsigned short* wfac;
  const float* bczr; const float* bgzr;
  float* zcon; float* xhcon; float* zgen; float* xhgen;
  float* conh; float* genh;
  unsigned short* genhb; unsigned short* agzr; unsigned short* achh; unsigned short* aghh;
  const unsigned short* zbuf;
  float* out;
  unsigned* gs;   // [0,16..112]=group counters, [128]=root, [144]=flag
};

enum { S_CZR=0, S_CHH=1, S_GZR=2, S_GHH=3, S_FAC=4 };

__device__ __forceinline__ void gbar(unsigned* gs, unsigned epoch) {
  __syncthreads();   // drains each wave's vmcnt -> all coherent stores complete
  if (threadIdx.x == 0) {
    const int grp = blockIdx.x & 7;
    unsigned p = __hip_atomic_fetch_add(&gs[grp*16], 1u, __ATOMIC_RELAXED, __HIP_MEMORY_SCOPE_AGENT);
    if (p + 1u == (NBLK/8u) * epoch) {
      unsigned q = __hip_atomic_fetch_add(&gs[128], 1u, __ATOMIC_RELAXED, __HIP_MEMORY_SCOPE_AGENT);
      if (q + 1u == 8u * epoch)
        __hip_atomic_store(&gs[144], epoch, __ATOMIC_RELAXED, __HIP_MEMORY_SCOPE_AGENT);
    }
    long guard = 0;
    for (;;) {
      unsigned v = __hip_atomic_load(&gs[144], __ATOMIC_RELAXED, __HIP_MEMORY_SCOPE_AGENT);
      if ((int)(v - epoch) >= 0) break;
      if (++guard > 20000000L) break;
      __builtin_amdgcn_s_sleep(2);
    }
  }
  __syncthreads();
}

template<int STAGE, int K, int NBN>
__device__ __forceinline__ void do_stage(const PA& a, int t) {
  // bijective XCD-chunked tile mapping: xcd x owns contiguous bn chunk
  constexpr int q = NBN >> 3, r = NBN & 7;
  const int x = blockIdx.x & 7, s = blockIdx.x >> 3;   // s in [0,24)
  const int nbx = q + (x < r ? 1 : 0);
  const int bl = s >> 3;
  if (bl >= nbx) return;
  const int bm = s & 7;
  const int bn = x*q + (x < r ? x : r) + bl;

  const unsigned short* w =
      STAGE == S_CZR ? a.wczr : STAGE == S_CHH ? a.wchh :
      STAGE == S_GZR ? a.wgzr : STAGE == S_GHH ? a.wghh : a.wfac;

  const int tid = threadIdx.x, lane = tid & 63, wid = tid >> 6;
  const int wm = wid >> 1, wn = wid & 1;
  const int l15 = lane & 15, ko = (lane >> 4) * 8;

  // batch rows (A operand; 2 M-frags) and weight cols (B operand; 4 N-frags)
  const int rA[2] = { bm*64 + wm*32 + l15, bm*64 + wm*32 + 16 + l15 };
  const unsigned short* wp[4];
  #pragma unroll
  for (int ni = 0; ni < 4; ++ni)
    wp[ni] = w + (size_t)(bn*128 + wn*64 + ni*16 + l15)*K + ko;

  // per-mi A region base pointers (selected per k)
  const unsigned short* A0[2]; const unsigned short* A1[2]; const unsigned short* A2[2];
  #pragma unroll
  for (int mi = 0; mi < 2; ++mi) {
    if constexpr (STAGE == S_CZR) {
      A0[mi] = a.cib   + ((size_t)rA[mi]*T_ + t)*CI_;
      A1[mi] = a.genhb + (size_t)rA[mi]*GEN_ - 128;
      A2[mi] = a.agzr  + (size_t)rA[mi]*CON_ - 928;
    } else if constexpr (STAGE == S_CHH) {
      A0[mi] = a.achh + (size_t)rA[mi]*416;  A1[mi] = A0[mi]; A2[mi] = A0[mi];
    } else if constexpr (STAGE == S_GZR) {
      A0[mi] = a.agzr  + (size_t)rA[mi]*CON_;
      A1[mi] = a.extb  + ((size_t)rA[mi]*T_ + t)*EXT_ - 400;
      A2[mi] = a.genhb + (size_t)rA[mi]*GEN_ - 416;
    } else {
      A0[mi] = (STAGE == S_GHH ? a.aghh : a.genhb) + (size_t)rA[mi]*GEN_;
      A1[mi] = A0[mi]; A2[mi] = A0[mi];
    }
  }

  f32x4 acc[2][4];
  #pragma unroll
  for (int i=0;i<2;++i)
    #pragma unroll
    for (int jj=0;jj<4;++jj) acc[i][jj] = (f32x4){0.f,0.f,0.f,0.f};

  constexpr int NK = K / 32;
  #pragma unroll 4
  for (int kt = 0; kt < NK; ++kt) {
    const int k = kt*32 + ko;
    short8 av[2], bv[4];
    #pragma unroll
    for (int ni = 0; ni < 4; ++ni)
      bv[ni] = *reinterpret_cast<const short8*>(wp[ni] + kt*32);
    #pragma unroll
    for (int mi = 0; mi < 2; ++mi) {
      const unsigned short* p;
      if constexpr (STAGE == S_CZR) {
        p = k < 128 ? A0[mi] + k : k < 928 ? A1[mi] + k
          : k < 1328 ? A2[mi] + k : a.zbuf;
      } else if constexpr (STAGE == S_GZR) {
        p = k < 400 ? A0[mi] + k : k < 408 ? A1[mi] + k
          : k < 416 ? a.zbuf : A2[mi] + k;
      } else {
        p = A0[mi] + k;
      }
      av[mi] = cld8(p);
    }
    #pragma unroll
    for (int mi = 0; mi < 2; ++mi)
      #pragma unroll
      for (int ni = 0; ni < 4; ++ni)   // swapped: D row = weight col, D col = batch
        acc[mi][ni] = __builtin_amdgcn_mfma_f32_16x16x32_bf16(bv[ni], av[mi], acc[mi][ni], 0,0,0);
  }

  const int lrow = (lane >> 4) * 4;
  #pragma unroll
  for (int mi = 0; mi < 2; ++mi) {
    const int bb = rA[mi];
    #pragma unroll
    for (int ni = 0; ni < 4; ++ni) {
      const int c0 = bn*128 + wn*64 + ni*16 + lrow;   // 4 consecutive cols c0..c0+3
      f32x4 vv = acc[mi][ni];
      if constexpr (STAGE == S_CZR) {
        if (c0 < 400) {
          #pragma unroll
          for (int j=0;j<4;++j) astf(&a.zcon[(size_t)bb*CON_ + c0+j], sigm(vv[j] + a.bczr[c0+j]));
        } else if (c0 < 800) {
          const int u0 = c0 - 400;
          float rh[4];
          #pragma unroll
          for (int j=0;j<4;++j)
            rh[j] = sigm(vv[j] + a.bczr[c0+j]) * aldf(&a.conh[(size_t)bb*CON_ + u0+j]);
          unsigned* dst = (unsigned*)a.achh + (size_t)bb*208 + (u0>>1);
          astu(dst, pk2(rh[0], rh[1])); astu(dst+1, pk2(rh[2], rh[3]));
        } else if (c0 < 1200) {
          #pragma unroll
          for (int j=0;j<4;++j) astf(&a.xhcon[(size_t)bb*CON_ + (c0-800)+j], vv[j] + a.bczr[c0+j]);
        } else if (c0 < 1328) {
          if (t > 0) {
            #pragma unroll
            for (int j=0;j<4;++j) a.out[((size_t)bb*T_ + (t-1))*FAC_ + (c0-1200)+j] = vv[j];
          }
        }
      } else if constexpr (STAGE == S_CHH) {
        if (c0 < 400) {
          float h[4];
          #pragma unroll
          for (int j=0;j<4;++j) {
            float xh = aldf(&a.xhcon[(size_t)bb*CON_ + c0+j]);
            float z  = aldf(&a.zcon [(size_t)bb*CON_ + c0+j]);
            float hp = aldf(&a.conh [(size_t)bb*CON_ + c0+j]);
            float hh = tanhf(vv[j] + xh);
            float hn = z*hp + (1.f - z)*hh;
            hn = fminf(fmaxf(hn, -5.f), 5.f);
            astf(&a.conh[(size_t)bb*CON_ + c0+j], hn);
            h[j] = hn;
          }
          unsigned* dst = (unsigned*)a.agzr + (size_t)bb*200 + (c0>>1);
          astu(dst, pk2(h[0], h[1])); astu(dst+1, pk2(h[2], h[3]));
        }
      } else if constexpr (STAGE == S_GZR) {
        if (c0 < 800) {
          #pragma unroll
          for (int j=0;j<4;++j) astf(&a.zgen[(size_t)bb*GEN_ + c0+j], sigm(vv[j] + a.bgzr[c0+j]));
        } else if (c0 < 1600) {
          const int u0 = c0 - 800;
          float rh[4];
          #pragma unroll
          for (int j=0;j<4;++j)
            rh[j] = sigm(vv[j] + a.bgzr[c0+j]) * aldf(&a.genh[(size_t)bb*GEN_ + u0+j]);
          unsigned* dst = (unsigned*)a.aghh + (size_t)bb*400 + (u0>>1);
          astu(dst, pk2(rh[0], rh[1])); astu(dst+1, pk2(rh[2], rh[3]));
        } else if (c0 < 2400) {
          #pragma unroll
          for (int j=0;j<4;++j) astf(&a.xhgen[(size_t)bb*GEN_ + (c0-1600)+j], vv[j] + a.bgzr[c0+j]);
        }
      } else if constexpr (STAGE == S_GHH) {
        if (c0 < 800) {
          float h[4];
          #pragma unroll
          for (int j=0;j<4;++j) {
            float xh = aldf(&a.xhgen[(size_t)bb*GEN_ + c0+j]);
            float z  = aldf(&a.zgen [(size_t)bb*GEN_ + c0+j]);
            float hp = aldf(&a.genh [(size_t)bb*GEN_ + c0+j]);
            float hh = tanhf(vv[j] + xh);
            float hn = z*hp + (1.f - z)*hh;
            hn = fminf(fmaxf(hn, -5.f), 5.f);
            astf(&a.genh[(size_t)bb*GEN_ + c0+j], hn);
            h[j] = hn;
          }
          unsigned* dst = (unsigned*)a.genhb + (size_t)bb*400 + (c0>>1);
          astu(dst, pk2(h[0], h[1])); astu(dst+1, pk2(h[2], h[3]));
        }
      } else { // S_FAC
        if (c0 < 128) {
          #pragma unroll
          for (int j=0;j<4;++j) a.out[((size_t)bb*T_ + (T_-1))*FAC_ + c0+j] = vv[j];
        }
      }
    }
  }
}

__global__ __launch_bounds__(256) void decoder_persist(PA a) {
  unsigned epoch = 0;
  for (int t = 0; t < T_; ++t) {
    do_stage<S_CZR, 1344, 11>(a, t);  gbar(a.gs, ++epoch);
    do_stage<S_CHH,  416,  4>(a, t);  gbar(a.gs, ++epoch);
    do_stage<S_GZR, 1216, 19>(a, t);  gbar(a.gs, ++epoch);
    do_stage<S_GHH,  800,  7>(a, t);  gbar(a.gs, ++epoch);
  }
  do_stage<S_FAC, 800, 1>(a, T_-1);
}

// ---------------- host ----------------

extern "C" void kernel_launch(void* const* d_in, const int* in_sizes, int n_in,
                              void* d_out, int out_size, void* d_ws, size_t ws_size,
                              hipStream_t stream) {
  const float* ci      = (const float*)d_in[0];
  const float* ext     = (const float*)d_in[1];
  const float* geninit = (const float*)d_in[2];
  const float* conh0   = (const float*)d_in[3];
  const float* conK    = (const float*)d_in[4];
  const float* conR    = (const float*)d_in[5];
  const float* conb    = (const float*)d_in[6];
  const float* comW    = (const float*)d_in[7];
  const float* comb    = (const float*)d_in[8];
  const float* genK    = (const float*)d_in[11];
  const float* genR    = (const float*)d_in[12];
  const float* genb    = (const float*)d_in[13];
  const float* facW    = (const float*)d_in[14];
  float* out = (float*)d_out;

  char* ws = (char*)d_ws;
  size_t off = 0;
  auto alloc = [&](size_t bytes) -> void* {
    void* p = ws + off;
    off = (off + bytes + 255) & ~(size_t)255;
    return p;
  };
  unsigned short* wczr  = (unsigned short*)alloc(1408UL*1344*2);
  unsigned short* wchh  = (unsigned short*)alloc(512UL*416*2);
  unsigned short* wgzr  = (unsigned short*)alloc(2432UL*1216*2);
  unsigned short* wghh  = (unsigned short*)alloc(896UL*800*2);
  unsigned short* wfac  = (unsigned short*)alloc(128UL*800*2);
  float* facWn = (float*)alloc(800UL*128*4);
  float* tmp2  = (float*)alloc(800UL*1200*4);
  float* tmp1  = (float*)alloc(400UL*2400*4);
  float* bczr  = (float*)alloc(1344UL*4);
  float* bgzr  = (float*)alloc(2432UL*4);
  float* conh  = (float*)alloc((size_t)B_*CON_*4);
  float* genh  = (float*)alloc((size_t)B_*GEN_*4);
  unsigned short* genhb = (unsigned short*)alloc((size_t)B_*GEN_*2);
  unsigned short* agzr  = (unsigned short*)alloc((size_t)B_*CON_*2);
  unsigned short* achh  = (unsigned short*)alloc((size_t)B_*416*2);
  unsigned short* aghh  = (unsigned short*)alloc((size_t)B_*GEN_*2);
  float* zcon  = (float*)alloc((size_t)B_*CON_*4);
  float* xhcon = (float*)alloc((size_t)B_*CON_*4);
  float* zgen  = (float*)alloc((size_t)B_*GEN_*4);
  float* xhgen = (float*)alloc((size_t)B_*GEN_*4);
  unsigned short* cib  = (unsigned short*)alloc((size_t)B_*T_*CI_*2);
  unsigned short* extb = (unsigned short*)alloc((size_t)B_*T_*EXT_*2);
  unsigned short* zbuf = (unsigned short*)alloc(64UL*2);
  unsigned* gsync      = (unsigned*)alloc(256UL*4);
  (void)ws_size; (void)in_sizes; (void)n_in; (void)out_size;

  dim3 blk(256);
  k_facnorm<<<dim3(128), dim3(64), 0, stream>>>(facW, facWn);
  k_w2<<<dim3(5, 800), blk, 0, stream>>>(facWn, conK, tmp2);
  k_w1<<<dim3(10, 400), blk, 0, stream>>>(comW, genK, tmp1);
  k_cvt<<<dim3(1024), blk, 0, stream>>>(ci, ext, cib, extb);
  k_init<<<dim3(2048), blk, 0, stream>>>(conh0, geninit, conb, genb, comb, genK,
                                         bczr, bgzr, conh, agzr, genh, genhb, achh,
                                         zbuf, gsync);

  BTArgs bt;
  bt.conK = conK; bt.conR = conR; bt.genK = genK; bt.genR = genR;
  bt.facWn = facWn; bt.tmp1 = tmp1; bt.tmp2 = tmp2;
  bt.mode = 0; bt.K = 1344; bt.dst = wczr; k_buildT<<<dim3(21,22), blk, 0, stream>>>(bt);
  bt.mode = 1; bt.K = 416;  bt.dst = wchh; k_buildT<<<dim3(7,8),   blk, 0, stream>>>(bt);
  bt.mode = 2; bt.K = 1216; bt.dst = wgzr; k_buildT<<<dim3(19,38), blk, 0, stream>>>(bt);
  bt.mode = 3; bt.K = 800;  bt.dst = wghh; k_buildT<<<dim3(13,14), blk, 0, stream>>>(bt);
  bt.mode = 4; bt.K = 800;  bt.dst = wfac; k_buildT<<<dim3(13,2),  blk, 0, stream>>>(bt);

  PA pa;
  pa.cib = cib; pa.extb = extb;
  pa.wczr = wczr; pa.wchh = wchh; pa.wgzr = wgzr; pa.wghh = wghh; pa.wfac = wfac;
  pa.bczr = bczr; pa.bgzr = bgzr;
  pa.zcon = zcon; pa.xhcon = xhcon; pa.zgen = zgen; pa.xhgen = xhgen;
  pa.conh = conh; pa.genh = genh;
  pa.genhb = genhb; pa.agzr = agzr; pa.achh = achh; pa.aghh = aghh;
  pa.zbuf = zbuf; pa.out = out; pa.gs = gsync;

  decoder_persist<<<dim3(NBLK), blk, 0, stream>>>(pa);
}

// Round 8
// 17748.108 us; speedup vs baseline: 3.2111x; 3.2111x over previous
//
#include <hip/hip_runtime.h>
#include <cstdint>
#include <cstddef>

// Decoder (LFADS-like): B=512, T=200.
// Persistent kernel v3.2 — per-XCD islands (r7 + the real fix):
//   * group g (= physical XCC_ID) owns rows [g*64, g*64+64); inter-stage
//     activations stay in XCD g's L2 (sc0 write-through stores; plain loads
//     made coherent by per-barrier `buffer_inv sc0` L0-invalidate).
//   * FIX vs r5/r6/r7: sync-cell READS must not be plain/sc0 loads — they
//     fill L0 and then poll stale L0 forever (no invalidate in the loop).
//     All sync reads now use `global_atomic_add(ptr, 0) sc0`, which executes
//     at the XCD's L2 and always returns the L2-fresh value.
//   * per-XCD barriers: sc0 atomics in the local L2; one-time agent-scope
//     registration barrier (relaxed, r4-proven) to settle slot/cnt.
// Precomposed weights:
//   W'  = com_W @ gen_K[:32]    (co_mean folded into generator GEMM)
//   W'' = fac_Wn @ con_K[128:]  (factor path folded into controller GEMM;
//                                fac_Wn columns appended -> facs for free)

#define B_   512
#define T_   200
#define CI_  128
#define EXT_ 8
#define GEN_ 800
#define CON_ 400
#define CO_  32
#define FAC_ 128
#define NBLK 256

typedef __attribute__((ext_vector_type(8))) short short8;
typedef __attribute__((ext_vector_type(4))) float f32x4;
typedef __attribute__((ext_vector_type(4))) unsigned short us4;
typedef unsigned short us;

__device__ __forceinline__ us f2bf(float f) {
  unsigned int u = __float_as_uint(f);
  u += 0x7FFFu + ((u >> 16) & 1u);   // RNE
  return (us)(u >> 16);
}
__device__ __forceinline__ unsigned pk2(float a, float b) {
  return (unsigned)f2bf(a) | ((unsigned)f2bf(b) << 16);
}
__device__ __forceinline__ float sigm(float x) { return 1.0f / (1.0f + __expf(-x)); }

// ---- sc0 (XCD-L2-coherent) primitives -------------------------------------
__device__ __forceinline__ void st128_sc0(void* p, f32x4 v) {
  asm volatile("global_store_dwordx4 %0, %1, off sc0" :: "v"(p), "v"(v) : "memory");
}
__device__ __forceinline__ void st64_sc0(void* p, unsigned lo, unsigned hi) {
  unsigned long long v = (unsigned long long)lo | ((unsigned long long)hi << 32);
  asm volatile("global_store_dwordx2 %0, %1, off sc0" :: "v"(p), "v"(v) : "memory");
}
__device__ __forceinline__ void st32_sc0(void* p, unsigned v) {
  asm volatile("global_store_dword %0, %1, off sc0" :: "v"(p), "v"(v) : "memory");
}
__device__ __forceinline__ unsigned atom_add_sc0(void* p, unsigned d) {
  unsigned old;
  asm volatile("global_atomic_add %0, %1, %2, off sc0\n\ts_waitcnt vmcnt(0)"
               : "=v"(old) : "v"(p), "v"(d) : "memory");
  return old;
}
// L2-fresh read: atomic add of 0 (atomics execute at the L2, never hit L0)
__device__ __forceinline__ unsigned ld_l2(void* p) { return atom_add_sc0(p, 0u); }

// ---------------- setup kernels ----------------

__global__ void k_facnorm(const float* __restrict__ facW, float* __restrict__ facWn) {
  int j = blockIdx.x;
  int l = threadIdx.x;
  float s = 0.f;
  for (int k = l; k < GEN_; k += 64) { float v = facW[(size_t)k*FAC_ + j]; s += v*v; }
  #pragma unroll
  for (int off = 32; off > 0; off >>= 1) s += __shfl_down(s, off, 64);
  float inv = 1.0f / sqrtf(__shfl(s, 0, 64));
  for (int k = l; k < GEN_; k += 64) facWn[(size_t)k*FAC_ + j] = facW[(size_t)k*FAC_ + j] * inv;
}

__global__ void k_w2(const float* __restrict__ facWn, const float* __restrict__ conK,
                     float* __restrict__ tmp2) {
  int n = blockIdx.x*256 + threadIdx.x; if (n >= 1200) return;
  int kp = blockIdx.y;
  const float* fr = facWn + (size_t)kp*FAC_;
  float s = 0.f;
  for (int j = 0; j < FAC_; ++j) s = fmaf(fr[j], conK[(size_t)(CI_+j)*1200 + n], s);
  tmp2[(size_t)kp*1200 + n] = s;
}

__global__ void k_w1(const float* __restrict__ comW, const float* __restrict__ genK,
                     float* __restrict__ tmp1) {
  int n = blockIdx.x*256 + threadIdx.x; if (n >= 2400) return;
  int k = blockIdx.y;
  const float* cr = comW + (size_t)k*CO_;
  float s = 0.f;
  for (int j = 0; j < CO_; ++j) s = fmaf(cr[j], genK[(size_t)j*2400 + n], s);
  tmp1[(size_t)k*2400 + n] = s;
}

__global__ void k_cvt(const float* __restrict__ ci, const float* __restrict__ ext,
                      us* __restrict__ cib, us* __restrict__ extb) {
  const long n1 = (long)B_*T_*CI_/4;
  const long n2 = (long)B_*T_*EXT_/4;
  for (long i = blockIdx.x*(long)blockDim.x + threadIdx.x; i < n1+n2;
       i += (long)gridDim.x*blockDim.x) {
    if (i < n1) {
      float4 f = reinterpret_cast<const float4*>(ci)[i];
      us4 u; u.x=f2bf(f.x); u.y=f2bf(f.y); u.z=f2bf(f.z); u.w=f2bf(f.w);
      reinterpret_cast<us4*>(cib)[i] = u;
    } else {
      long k = i - n1;
      float4 f = reinterpret_cast<const float4*>(ext)[k];
      us4 u; u.x=f2bf(f.x); u.y=f2bf(f.y); u.z=f2bf(f.z); u.w=f2bf(f.w);
      reinterpret_cast<us4*>(extb)[k] = u;
    }
  }
}

__global__ void k_init(const float* __restrict__ conh0, const float* __restrict__ geninit,
                       const float* __restrict__ conb, const float* __restrict__ genb,
                       const float* __restrict__ comb, const float* __restrict__ genK,
                       float* __restrict__ bczr, float* __restrict__ bgzr,
                       float* __restrict__ conh, us* __restrict__ agzr,
                       float* __restrict__ genh, us* __restrict__ genhb,
                       us* __restrict__ achh,
                       us* __restrict__ zbuf, unsigned* __restrict__ gs) {
  const long R0=1344, R1=2432, R2=(long)B_*CON_, R3=(long)B_*CON_,
             R4=(long)B_*GEN_, R5=(long)B_*GEN_, R6=(long)B_*416, R7=64, R8=2048;
  const long total = R0+R1+R2+R3+R4+R5+R6+R7+R8;
  for (long idx = blockIdx.x*(long)blockDim.x + threadIdx.x; idx < total;
       idx += (long)gridDim.x*blockDim.x) {
    long i = idx;
    if (i < R0) { bczr[i] = (i < 1200) ? conb[i] : 0.f; continue; }
    i -= R0;
    if (i < R1) {
      float s = 0.f;
      if (i < 2400) { s = genb[i]; for (int j=0;j<32;++j) s = fmaf(comb[j], genK[(size_t)j*2400 + i], s); }
      bgzr[i] = s; continue;
    }
    i -= R1;
    if (i < R2) { conh[i] = conh0[i % CON_]; continue; }
    i -= R2;
    if (i < R3) { agzr[i] = f2bf(conh0[i % CON_]); continue; }
    i -= R3;
    if (i < R4) { genh[i] = geninit[i]; continue; }
    i -= R4;
    if (i < R5) { genhb[i] = f2bf(geninit[i]); continue; }
    i -= R5;
    if (i < R6) { achh[i] = 0; continue; }
    i -= R6;
    if (i < R7) { zbuf[i] = 0; continue; }
    i -= R7;
    gs[i] = 0;
  }
}

// build transposed bf16 weights: dst[n][k] = fetch(k, n)
struct BTArgs {
  int mode, K;
  const float* conK; const float* conR; const float* genK; const float* genR;
  const float* facWn; const float* tmp1; const float* tmp2;
  us* dst;
};

__device__ __forceinline__ float bt_fetch(const BTArgs& a, int k, int n) {
  switch (a.mode) {
    case 0: // W_czr^T: K=1344 (ci128|gen800|con416), N=1408 (z400|r400|xh400|fac128|pad)
      if (n < 1200) {
        if (k < 128)  return a.conK[(size_t)k*1200 + n];
        if (k < 928)  return a.tmp2[(size_t)(k-128)*1200 + n];
        if (k < 1328) return (n < 800) ? a.conR[(size_t)(k-928)*1200 + n] : 0.f;
        return 0.f;
      }
      if (n < 1328) return (k >= 128 && k < 928) ? a.facWn[(size_t)(k-128)*FAC_ + (n-1200)] : 0.f;
      return 0.f;
    case 1: // W_chh^T: con_R[:,800:1200]
      return (k < 400 && n < 400) ? a.conR[(size_t)k*1200 + 800 + n] : 0.f;
    case 2: // W_gzr^T: K=1216 (conh400|ext8|pad8|genh800), N=2432 (z800|r800|xh800|pad)
      if (n >= 2400) return 0.f;
      if (k < 400)  return a.tmp1[(size_t)k*2400 + n];
      if (k < 408)  return a.genK[(size_t)(32 + k - 400)*2400 + n];
      if (k < 416)  return 0.f;
      if (k < 1216) return (n < 1600) ? a.genR[(size_t)(k-416)*2400 + n] : 0.f;
      return 0.f;
    case 3: // W_ghh^T: gen_R[:,1600:2400]
      return (n < 800 && k < 800) ? a.genR[(size_t)k*2400 + 1600 + n] : 0.f;
    default: // fac_Wn^T [192 pad][800]
      return (k < 800 && n < 128) ? a.facWn[(size_t)k*FAC_ + n] : 0.f;
  }
}

__global__ __launch_bounds__(256) void k_buildT(BTArgs a) {
  __shared__ float tile[64][65];
  int k0 = blockIdx.x*64, n0 = blockIdx.y*64;
  int tid = threadIdx.x;
  int rr = tid >> 2, cc = (tid & 3) * 16;
  #pragma unroll 4
  for (int i = 0; i < 16; ++i) tile[rr][cc+i] = bt_fetch(a, k0+rr, n0+cc+i);
  __syncthreads();
  int n = n0 + rr;
  if (k0 + cc < a.K) {
    short8 v0, v1;
    #pragma unroll
    for (int i = 0; i < 8; ++i) v0[i] = (short)f2bf(tile[cc+i][rr]);
    #pragma unroll
    for (int i = 0; i < 8; ++i) v1[i] = (short)f2bf(tile[cc+8+i][rr]);
    *reinterpret_cast<short8*>(&a.dst[(size_t)n*a.K + k0 + cc])     = v0;
    *reinterpret_cast<short8*>(&a.dst[(size_t)n*a.K + k0 + cc + 8]) = v1;
  }
}

// ---------------- persistent decoder ----------------

struct PA {
  const us* cib; const us* extb;
  const us* wczr; const us* wchh; const us* wgzr; const us* wghh; const us* wfac;
  const float* bczr; const float* bgzr;
  float* zcon; float* xhcon; float* zgen; float* xhgen;
  float* conh; float* genh;
  us* genhb; us* agzr; us* achh; us* aghh;
  const us* zbuf;
  float* out;
  // sync cells, 256 B apart (one XCD per line):
  // arrive[g] @ g*64, flag[g] @ 512+g*64, slotcnt[g] @ 1024+g*64, root @ 1536
  unsigned* gs;
};

enum { S_CZR=0, S_CHH=1, S_GZR=2, S_GHH=3, S_FAC=4 };

// per-XCD barrier: arrive/poll via sc0 ATOMICS in the local L2 (L2-fresh),
// then L0-only invalidate so subsequent plain loads see the new activations.
__device__ __forceinline__ void gbar(unsigned* gs, int g, unsigned cnt, unsigned ep) {
  asm volatile("s_waitcnt vmcnt(0)" ::: "memory");   // this wave's stores in L2
  __syncthreads();                                   // all waves drained
  if (threadIdx.x == 0) {
    unsigned old = atom_add_sc0(&gs[g*64], 1u);
    if (old + 1u >= cnt * ep) st32_sc0(&gs[512 + g*64], ep);
    long guard = 0;
    for (;;) {
      unsigned v = ld_l2(&gs[512 + g*64]);           // atomic add 0 -> L2-fresh
      if ((int)(v - ep) >= 0) break;
      if (++guard > 300000L) break;                  // slow-fail, never hang
      __builtin_amdgcn_s_sleep(1);
    }
  }
  __syncthreads();
  asm volatile("buffer_inv sc0" ::: "memory");       // L0-only invalidate
}

template<int STAGE>
__device__ __forceinline__ void epi(const PA& a, int t, int bb, int c0, f32x4 v) {
  if constexpr (STAGE == S_CZR) {
    if (c0 < 400) {
      float4 b = *reinterpret_cast<const float4*>(&a.bczr[c0]);
      f32x4 z = { sigm(v[0]+b.x), sigm(v[1]+b.y), sigm(v[2]+b.z), sigm(v[3]+b.w) };
      st128_sc0(&a.zcon[(size_t)bb*CON_ + c0], z);
    } else if (c0 < 800) {
      float4 b = *reinterpret_cast<const float4*>(&a.bczr[c0]);
      int u0 = c0 - 400;
      float4 hp = *reinterpret_cast<const float4*>(&a.conh[(size_t)bb*CON_ + u0]);
      float r0 = sigm(v[0]+b.x)*hp.x, r1 = sigm(v[1]+b.y)*hp.y;
      float r2 = sigm(v[2]+b.z)*hp.z, r3 = sigm(v[3]+b.w)*hp.w;
      st64_sc0(&a.achh[(size_t)bb*416 + u0], pk2(r0,r1), pk2(r2,r3));
    } else if (c0 < 1200) {
      float4 b = *reinterpret_cast<const float4*>(&a.bczr[c0]);
      f32x4 x = { v[0]+b.x, v[1]+b.y, v[2]+b.z, v[3]+b.w };
      st128_sc0(&a.xhcon[(size_t)bb*CON_ + (c0-800)], x);
    } else if (c0 < 1328) {
      if (t > 0) {
        float4* o = reinterpret_cast<float4*>(&a.out[((size_t)bb*T_ + (t-1))*FAC_ + (c0-1200)]);
        *o = make_float4(v[0], v[1], v[2], v[3]);
      }
    }
  } else if constexpr (STAGE == S_CHH) {
    if (c0 < 400) {
      float4 xh = *reinterpret_cast<const float4*>(&a.xhcon[(size_t)bb*CON_ + c0]);
      float4 zz = *reinterpret_cast<const float4*>(&a.zcon [(size_t)bb*CON_ + c0]);
      float4 hp = *reinterpret_cast<const float4*>(&a.conh [(size_t)bb*CON_ + c0]);
      float h[4]; float xs[4] = {xh.x,xh.y,xh.z,xh.w};
      float zs[4] = {zz.x,zz.y,zz.z,zz.w}; float hs[4] = {hp.x,hp.y,hp.z,hp.w};
      #pragma unroll
      for (int j=0;j<4;++j) {
        float hh = tanhf(v[j] + xs[j]);
        float hn = zs[j]*hs[j] + (1.f - zs[j])*hh;
        h[j] = fminf(fmaxf(hn, -5.f), 5.f);
      }
      st128_sc0(&a.conh[(size_t)bb*CON_ + c0], (f32x4){h[0],h[1],h[2],h[3]});
      st64_sc0(&a.agzr[(size_t)bb*CON_ + c0], pk2(h[0],h[1]), pk2(h[2],h[3]));
    }
  } else if constexpr (STAGE == S_GZR) {
    if (c0 < 800) {
      float4 b = *reinterpret_cast<const float4*>(&a.bgzr[c0]);
      f32x4 z = { sigm(v[0]+b.x), sigm(v[1]+b.y), sigm(v[2]+b.z), sigm(v[3]+b.w) };
      st128_sc0(&a.zgen[(size_t)bb*GEN_ + c0], z);
    } else if (c0 < 1600) {
      float4 b = *reinterpret_cast<const float4*>(&a.bgzr[c0]);
      int u0 = c0 - 800;
      float4 hp = *reinterpret_cast<const float4*>(&a.genh[(size_t)bb*GEN_ + u0]);
      float r0 = sigm(v[0]+b.x)*hp.x, r1 = sigm(v[1]+b.y)*hp.y;
      float r2 = sigm(v[2]+b.z)*hp.z, r3 = sigm(v[3]+b.w)*hp.w;
      st64_sc0(&a.aghh[(size_t)bb*GEN_ + u0], pk2(r0,r1), pk2(r2,r3));
    } else if (c0 < 2400) {
      float4 b = *reinterpret_cast<const float4*>(&a.bgzr[c0]);
      f32x4 x = { v[0]+b.x, v[1]+b.y, v[2]+b.z, v[3]+b.w };
      st128_sc0(&a.xhgen[(size_t)bb*GEN_ + (c0-1600)], x);
    }
  } else if constexpr (STAGE == S_GHH) {
    if (c0 < 800) {
      float4 xh = *reinterpret_cast<const float4*>(&a.xhgen[(size_t)bb*GEN_ + c0]);
      float4 zz = *reinterpret_cast<const float4*>(&a.zgen [(size_t)bb*GEN_ + c0]);
      float4 hp = *reinterpret_cast<const float4*>(&a.genh [(size_t)bb*GEN_ + c0]);
      float h[4]; float xs[4] = {xh.x,xh.y,xh.z,xh.w};
      float zs[4] = {zz.x,zz.y,zz.z,zz.w}; float hs[4] = {hp.x,hp.y,hp.z,hp.w};
      #pragma unroll
      for (int j=0;j<4;++j) {
        float hh = tanhf(v[j] + xs[j]);
        float hn = zs[j]*hs[j] + (1.f - zs[j])*hh;
        h[j] = fminf(fmaxf(hn, -5.f), 5.f);
      }
      st128_sc0(&a.genh[(size_t)bb*GEN_ + c0], (f32x4){h[0],h[1],h[2],h[3]});
      st64_sc0(&a.genhb[(size_t)bb*GEN_ + c0], pk2(h[0],h[1]), pk2(h[2],h[3]));
    }
  } else { // S_FAC
    if (c0 < 128) {
      float4* o = reinterpret_cast<float4*>(&a.out[((size_t)bb*T_ + (T_-1))*FAC_ + c0]);
      *o = make_float4(v[0], v[1], v[2], v[3]);
    }
  }
}

template<int STAGE, int K, int F>
__device__ __forceinline__ void do_stage(const PA& a, int t, int g, int slot, int cnt) {
  const int lane = threadIdx.x & 63, wid = threadIdx.x >> 6;
  int base = (int)((long)slot * F / cnt);
  int end  = (int)((long)(slot+1) * F / cnt);
  if (end > F) end = F;
  if (base >= end) return;

  const us* warr =
      STAGE == S_CZR ? a.wczr : STAGE == S_CHH ? a.wchh :
      STAGE == S_GZR ? a.wgzr : STAGE == S_GHH ? a.wghh : a.wfac;

  const int l15 = lane & 15, ko = (lane >> 4) * 8;
  const int bb = g*64 + wid*16 + l15;    // this lane's batch row (D col)

  const us *A0 = nullptr, *A1 = nullptr, *A2 = nullptr;
  if constexpr (STAGE == S_CZR) {
    A0 = a.cib   + ((size_t)bb*T_ + t)*CI_;
    A1 = a.genhb + (size_t)bb*GEN_ - 128;
    A2 = a.agzr  + (size_t)bb*CON_ - 928;
  } else if constexpr (STAGE == S_CHH) {
    A0 = a.achh + (size_t)bb*416;
  } else if constexpr (STAGE == S_GZR) {
    A0 = a.agzr  + (size_t)bb*CON_;
    A1 = a.extb  + ((size_t)bb*T_ + t)*EXT_ - 400;
    A2 = a.genhb + (size_t)bb*GEN_ - 416;
  } else if constexpr (STAGE == S_GHH) {
    A0 = a.aghh + (size_t)bb*GEN_;
  } else {
    A0 = a.genhb + (size_t)bb*GEN_;
  }

  for (int nf = base; nf < end; nf += 2) {
    const us* wp0 = warr + (size_t)(nf*16 + l15)*K + ko;
    const us* wp1 = wp0 + (size_t)16*K;
    f32x4 acc0 = {0.f,0.f,0.f,0.f}, acc1 = {0.f,0.f,0.f,0.f};
    #pragma unroll 4
    for (int kt = 0; kt < K/32; ++kt) {
      const int k0 = kt*32 + ko;
      const us* p;
      if constexpr (STAGE == S_CZR) {
        p = k0 < 128 ? A0 + k0 : k0 < 928 ? A1 + k0
          : k0 < 1328 ? A2 + k0 : a.zbuf;
      } else if constexpr (STAGE == S_GZR) {
        p = k0 < 400 ? A0 + k0 : k0 < 408 ? A1 + k0
          : k0 < 416 ? a.zbuf : A2 + k0;
      } else {
        p = A0 + k0;
      }
      short8 av  = *reinterpret_cast<const short8*>(p);
      short8 bv0 = *reinterpret_cast<const short8*>(wp0 + kt*32);
      short8 bv1 = *reinterpret_cast<const short8*>(wp1 + kt*32);
      acc0 = __builtin_amdgcn_mfma_f32_16x16x32_bf16(bv0, av, acc0, 0,0,0);
      acc1 = __builtin_amdgcn_mfma_f32_16x16x32_bf16(bv1, av, acc1, 0,0,0);
    }
    const int cq = (lane >> 4) * 4;
    epi<STAGE>(a, t, bb, nf*16 + cq, acc0);
    if (nf + 1 < end) epi<STAGE>(a, t, bb, (nf+1)*16 + cq, acc1);
  }
}

__global__ __launch_bounds__(256) void decoder_persist(PA a) {
  const int tid = threadIdx.x;
  unsigned xcc;
  asm("s_getreg_b32 %0, hwreg(HW_REG_XCC_ID)" : "=s"(xcc));
  const int g = (int)(xcc & 7u);

  __shared__ int s_slot, s_cnt;
  if (tid == 0) {
    s_slot = (int)atom_add_sc0(&a.gs[1024 + g*64], 1u);
  }
  __syncthreads();
  if (tid == 0) {
    // one-time global registration barrier (relaxed agent scope, r4-proven)
    __hip_atomic_fetch_add(&a.gs[1536], 1u, __ATOMIC_RELAXED, __HIP_MEMORY_SCOPE_AGENT);
    long guard = 0;
    for (;;) {
      unsigned v = __hip_atomic_load(&a.gs[1536], __ATOMIC_RELAXED, __HIP_MEMORY_SCOPE_AGENT);
      if (v >= (unsigned)NBLK) break;
      if (++guard > 20000000L) break;
      __builtin_amdgcn_s_sleep(1);
    }
    int c = (int)ld_l2(&a.gs[1024 + g*64]);   // L2-fresh group count
    s_cnt = c < 1 ? 1 : c;
  }
  __syncthreads();
  const int slot = s_slot;
  const unsigned cnt = (unsigned)s_cnt;
  asm volatile("buffer_inv sc0" ::: "memory");

  unsigned ep = 0;
  for (int t = 0; t < T_; ++t) {
    do_stage<S_CZR, 1344,  83>(a, t, g, slot, (int)cnt);  gbar(a.gs, g, cnt, ++ep);
    do_stage<S_CHH,  416,  25>(a, t, g, slot, (int)cnt);  gbar(a.gs, g, cnt, ++ep);
    do_stage<S_GZR, 1216, 150>(a, t, g, slot, (int)cnt);  gbar(a.gs, g, cnt, ++ep);
    do_stage<S_GHH,  800,  50>(a, t, g, slot, (int)cnt);  gbar(a.gs, g, cnt, ++ep);
  }
  do_stage<S_FAC, 800, 8>(a, T_-1, g, slot, (int)cnt);
}

// ---------------- host ----------------

extern "C" void kernel_launch(void* const* d_in, const int* in_sizes, int n_in,
                              void* d_out, int out_size, void* d_ws, size_t ws_size,
                              hipStream_t stream) {
  const float* ci      = (const float*)d_in[0];
  const float* ext     = (const float*)d_in[1];
  const float* geninit = (const float*)d_in[2];
  const float* conh0   = (const float*)d_in[3];
  const float* conK    = (const float*)d_in[4];
  const float* conR    = (const float*)d_in[5];
  const float* conb    = (const float*)d_in[6];
  const float* comW    = (const float*)d_in[7];
  const float* comb    = (const float*)d_in[8];
  const float* genK    = (const float*)d_in[11];
  const float* genR    = (const float*)d_in[12];
  const float* genb    = (const float*)d_in[13];
  const float* facW    = (const float*)d_in[14];
  float* out = (float*)d_out;

  char* ws = (char*)d_ws;
  size_t off = 0;
  auto alloc = [&](size_t bytes) -> void* {
    void* p = ws + off;
    off = (off + bytes + 255) & ~(size_t)255;
    return p;
  };
  us* wczr  = (us*)alloc(1408UL*1344*2);
  us* wchh  = (us*)alloc(512UL*416*2);
  us* wgzr  = (us*)alloc(2432UL*1216*2);
  us* wghh  = (us*)alloc(896UL*800*2);
  us* wfac  = (us*)alloc(192UL*800*2);
  float* facWn = (float*)alloc(800UL*128*4);
  float* tmp2  = (float*)alloc(800UL*1200*4);
  float* tmp1  = (float*)alloc(400UL*2400*4);
  float* bczr  = (float*)alloc(1344UL*4);
  float* bgzr  = (float*)alloc(2432UL*4);
  float* conh  = (float*)alloc((size_t)B_*CON_*4);
  float* genh  = (float*)alloc((size_t)B_*GEN_*4);
  us* genhb = (us*)alloc((size_t)B_*GEN_*2);
  us* agzr  = (us*)alloc((size_t)B_*CON_*2);
  us* achh  = (us*)alloc((size_t)B_*416*2);
  us* aghh  = (us*)alloc((size_t)B_*GEN_*2);
  float* zcon  = (float*)alloc((size_t)B_*CON_*4);
  float* xhcon = (float*)alloc((size_t)B_*CON_*4);
  float* zgen  = (float*)alloc((size_t)B_*GEN_*4);
  float* xhgen = (float*)alloc((size_t)B_*GEN_*4);
  us* cib  = (us*)alloc((size_t)B_*T_*CI_*2);
  us* extb = (us*)alloc((size_t)B_*T_*EXT_*2);
  us* zbuf = (us*)alloc(64UL*2);
  unsigned* gsync = (unsigned*)alloc(2048UL*4);
  (void)ws_size; (void)in_sizes; (void)n_in; (void)out_size;

  dim3 blk(256);
  k_facnorm<<<dim3(128), dim3(64), 0, stream>>>(facW, facWn);
  k_w2<<<dim3(5, 800), blk, 0, stream>>>(facWn, conK, tmp2);
  k_w1<<<dim3(10, 400), blk, 0, stream>>>(comW, genK, tmp1);
  k_cvt<<<dim3(1024), blk, 0, stream>>>(ci, ext, cib, extb);
  k_init<<<dim3(2048), blk, 0, stream>>>(conh0, geninit, conb, genb, comb, genK,
                                         bczr, bgzr, conh, agzr, genh, genhb, achh,
                                         zbuf, gsync);

  BTArgs bt;
  bt.conK = conK; bt.conR = conR; bt.genK = genK; bt.genR = genR;
  bt.facWn = facWn; bt.tmp1 = tmp1; bt.tmp2 = tmp2;
  bt.mode = 0; bt.K = 1344; bt.dst = wczr; k_buildT<<<dim3(21,22), blk, 0, stream>>>(bt);
  bt.mode = 1; bt.K = 416;  bt.dst = wchh; k_buildT<<<dim3(7,8),   blk, 0, stream>>>(bt);
  bt.mode = 2; bt.K = 1216; bt.dst = wgzr; k_buildT<<<dim3(19,38), blk, 0, stream>>>(bt);
  bt.mode = 3; bt.K = 800;  bt.dst = wghh; k_buildT<<<dim3(13,14), blk, 0, stream>>>(bt);
  bt.mode = 4; bt.K = 800;  bt.dst = wfac; k_buildT<<<dim3(13,3),  blk, 0, stream>>>(bt);

  PA pa;
  pa.cib = cib; pa.extb = extb;
  pa.wczr = wczr; pa.wchh = wchh; pa.wgzr = wgzr; pa.wghh = wghh; pa.wfac = wfac;
  pa.bczr = bczr; pa.bgzr = bgzr;
  pa.zcon = zcon; pa.xhcon = xhcon; pa.zgen = zgen; pa.xhgen = xhgen;
  pa.conh = conh; pa.genh = genh;
  pa.genhb = genhb; pa.agzr = agzr; pa.achh = achh; pa.aghh = aghh;
  pa.zbuf = zbuf; pa.out = out; pa.gs = gsync;

  decoder_persist<<<dim3(NBLK), blk, 0, stream>>>(pa);
}